// Round 1
// baseline (109.421 us; speedup 1.0000x reference)
//
#include <hip/hip_runtime.h>
#include <hip/hip_fp16.h>

#define B_SZ    16384
#define NNZ_PER 32
#define F_DIM   768
#define H_DIM   512

typedef unsigned int  uint32;
typedef unsigned long long uint64;
typedef unsigned char uchar;

// ---------------------------------------------------------------------------
// fp32 -> fp8 e5m2 (RNE): e5m2 is the top byte of fp16. Decode (byte<<8) is
// exact fp16. Weights ~N(0,0.02): no overflow/subnormal trouble.
// ---------------------------------------------------------------------------
__device__ inline uchar f32_to_e5m2(float x) {
    __half h = __float2half_rn(x);
    unsigned short hb = *(unsigned short*)&h;
    unsigned short lsb = (hb >> 8) & 1;
    hb = (unsigned short)(hb + 0x7F + lsb);   // RNE into top 8 bits
    return (uchar)(hb >> 8);
}

__global__ __launch_bounds__(256) void transpose_convert(
    const float* __restrict__ W, uchar* __restrict__ Wt8)
{
    __shared__ float tile[32][33];
    const int f0 = blockIdx.x * 32;
    const int h0 = blockIdx.y * 32;
    const int tx = threadIdx.x;
    const int ty = threadIdx.y;

#pragma unroll
    for (int i = 0; i < 32; i += 8)
        tile[ty + i][tx] = W[(h0 + ty + i) * F_DIM + f0 + tx];
    __syncthreads();
#pragma unroll
    for (int i = 0; i < 32; i += 8)
        Wt8[(size_t)(f0 + ty + i) * H_DIM + h0 + tx] = f32_to_e5m2(tile[tx][ty + i]);
}

// ---------------------------------------------------------------------------
// Main: H-split for occupancy. 2 positions per 256-thread block; each
// position is handled by TWO waves, each owning one half of H (256 cols,
// 8 h per lane). Same total L2 traffic and identical fp16 accumulation
// order as the 1-wave/position version, but the load pipeline only needs
// uint2 buffers (48 VGPRs vs 80), so we fit 6 waves/SIMD (24 waves/CU,
// was 16) for +50% gather-latency tolerance.
// Lanes 0-31 even feature slots, 32-63 odd; lane c owns h = hh*256+c*8..+7.
// ---------------------------------------------------------------------------
__global__ __launch_bounds__(256, 6) void nnue_fwd(
    const int*   __restrict__ stm_idx,
    const int*   __restrict__ nstm_idx,
    const float* __restrict__ stm_val,
    const float* __restrict__ nstm_val,
    const uchar* __restrict__ Wt8,        // [F][H] e5m2
    const float* __restrict__ b_ft,
    const float* __restrict__ W_out,
    const float* __restrict__ b_out,
    float* __restrict__ out)
{
    const int tid  = threadIdx.x;
    const int w    = tid >> 6;      // wave 0..3
    const int pos  = w >> 1;        // position within block: 0..1
    const int hh   = w & 1;         // which half of H this wave owns
    const int lane = tid & 63;
    const int half = lane >> 5;     // feature-slot parity group
    const int c    = lane & 31;
    const int b    = blockIdx.x * 2 + pos;
    const int NNZ  = B_SZ * NNZ_PER;

    __shared__ uint64 sh[2][64];    // per position: 0-31 stm, 32-63 nstm: {half2(v,v), f}
    __shared__ float  pdot[2][2];   // per position: partial dot from each H-half wave

    if (tid < 128) {
        const int p    = tid >> 6;
        const int s    = tid & 63;
        const int base = (blockIdx.x * 2 + p) * NNZ_PER;
        int f; float v;
        if (s < 32) { f = stm_idx [NNZ + base + s];        v = stm_val [base + s]; }
        else        { f = nstm_idx[NNZ + base + (s - 32)]; v = nstm_val[base + (s - 32)]; }
        __half2 vv = __float2half2_rn(v);
        sh[p][s] = ((uint64)(*(uint32*)&vv) << 32) | (uint32)f;
    }
    __syncthreads();

    const uint32 selA = 0x01040004u;   // [0,b0,0,b1] -> half2(h0,h1)
    const uint32 selB = 0x03040204u;   // [0,b2,0,b3] -> half2(h2,h3)
    const uint32 coff = ((uint32)hh << 8) | ((uint32)c << 3);   // byte offset in row
    const char*  Wb   = (const char*)Wt8;

    __half2 z = __float2half2_rn(0.f);
    __half2 sa[4] = {z, z, z, z};
    __half2 na[4] = {z, z, z, z};

    // Double-buffered pipeline: 8 uint2 loads per group, 16 in flight.
    uint2   bufA[8], bufB[8];
    __half2 valA[8], valB[8];

    // g: group 0..3. Pair index for slot i: stm j = 4*g+i (i<4), nstm j = 4*g+(i-4).
#define LOAD_GROUP(g, BUF, VAL)                                               \
    {                                                                         \
        _Pragma("unroll")                                                     \
        for (int i = 0; i < 8; ++i) {                                         \
            const int j = 4 * (g) + (i & 3);                                  \
            const int slot = (i < 4 ? 0 : 32) + 2 * j + half;                 \
            uint64 e  = sh[pos][slot];                                        \
            uint32 f  = (uint32)e;                                            \
            uint32 v2 = (uint32)(e >> 32);                                    \
            VAL[i] = *(__half2*)&v2;                                          \
            uint32 off = (f << 9) | coff;                                     \
            BUF[i] = *(const uint2*)(Wb + off);                               \
        }                                                                     \
    }

#define FMA_GROUP(BUF, VAL)                                                   \
    {                                                                         \
        _Pragma("unroll")                                                     \
        for (int i = 0; i < 8; ++i) {                                         \
            __half2* acc = (i < 4) ? sa : na;                                 \
            uint2 wv = BUF[i];                                                \
            __half2 vv = VAL[i];                                              \
            uint32 p;                                                         \
            p = __builtin_amdgcn_perm(0u, wv.x, selA); acc[0] = __hfma2(*(__half2*)&p, vv, acc[0]); \
            p = __builtin_amdgcn_perm(0u, wv.x, selB); acc[1] = __hfma2(*(__half2*)&p, vv, acc[1]); \
            p = __builtin_amdgcn_perm(0u, wv.y, selA); acc[2] = __hfma2(*(__half2*)&p, vv, acc[2]); \
            p = __builtin_amdgcn_perm(0u, wv.y, selB); acc[3] = __hfma2(*(__half2*)&p, vv, acc[3]); \
        }                                                                     \
    }

    LOAD_GROUP(0, bufA, valA);
    LOAD_GROUP(1, bufB, valB);
    FMA_GROUP(bufA, valA);
    LOAD_GROUP(2, bufA, valA);
    FMA_GROUP(bufB, valB);
    LOAD_GROUP(3, bufB, valB);
    FMA_GROUP(bufA, valA);
    FMA_GROUP(bufB, valB);

#undef LOAD_GROUP
#undef FMA_GROUP

    // Epilogue, on the fly (keeps VGPRs low). Cross-half combine in fp32
    // (lane ^ 32 holds the other feature parity, same h-range). Lanes with
    // half=0 dot the stm side against W_out[0:512), half=1 the nstm side
    // against W_out[512:1024) — the full-wave reduce sums both.
    const float* bias = b_ft  + (hh << 8) + (c << 3);
    const float* wo   = W_out + half * H_DIM + (hh << 8) + (c << 3);
    float dot = 0.f;
#pragma unroll
    for (int k = 0; k < 4; ++k) {
        int ms = *(int*)&sa[k];
        int mn = *(int*)&na[k];
        int os = __shfl_xor(ms, 32, 64);
        int on = __shfl_xor(mn, 32, 64);
        int mm = half ? mn : ms;
        int oo = half ? on : os;
        __half2 mh = *(__half2*)&mm;
        __half2 oh = *(__half2*)&oo;
        float h0 = __low2float(mh)  + __low2float(oh);
        float h1 = __high2float(mh) + __high2float(oh);
        float a0 = fminf(fmaxf(h0 + bias[2 * k],     0.f), 1.f);
        float a1 = fminf(fmaxf(h1 + bias[2 * k + 1], 0.f), 1.f);
        dot += a0 * wo[2 * k] + a1 * wo[2 * k + 1];
    }

#pragma unroll
    for (int off = 32; off > 0; off >>= 1)
        dot += __shfl_xor(dot, off, 64);

    if (lane == 0)
        pdot[pos][hh] = dot;
    __syncthreads();

    if (hh == 0 && lane == 0) {
        float d = pdot[pos][0] + pdot[pos][1] + b_out[0];
        out[b] = 1.f / (1.f + expf(-d));
    }
}

extern "C" void kernel_launch(void* const* d_in, const int* in_sizes, int n_in,
                              void* d_out, int out_size, void* d_ws, size_t ws_size,
                              hipStream_t stream) {
    const int*   stm_idx  = (const int*)  d_in[0];
    const int*   nstm_idx = (const int*)  d_in[1];
    const float* stm_val  = (const float*)d_in[2];
    const float* nstm_val = (const float*)d_in[3];
    const float* W_ft     = (const float*)d_in[5];
    const float* b_ft     = (const float*)d_in[6];
    const float* W_out    = (const float*)d_in[7];
    const float* b_out    = (const float*)d_in[8];
    float*       out      = (float*)d_out;
    uchar*       Wt8      = (uchar*)d_ws;   // 384 KiB

    dim3 tb(32, 8);
    dim3 tg(F_DIM / 32, H_DIM / 32);
    transpose_convert<<<tg, tb, 0, stream>>>(W_ft, Wt8);

    nnue_fwd<<<B_SZ / 2, 256, 0, stream>>>(stm_idx, nstm_idx, stm_val, nstm_val,
                                           Wt8, b_ft, W_out, b_out, out);
}

// Round 2
// 100.579 us; speedup vs baseline: 1.0879x; 1.0879x over previous
//
#include <hip/hip_runtime.h>
#include <hip/hip_fp16.h>

#define B_SZ    16384
#define NNZ_PER 32
#define F_DIM   768
#define H_DIM   512

typedef unsigned int  uint32;
typedef unsigned long long uint64;
typedef unsigned char uchar;

// ---------------------------------------------------------------------------
// fp32 -> fp8 e5m2 (RNE): e5m2 is the top byte of fp16. Decode (byte<<8) is
// exact fp16. Weights ~N(0,0.02): no overflow/subnormal trouble.
// ---------------------------------------------------------------------------
__device__ inline uchar f32_to_e5m2(float x) {
    __half h = __float2half_rn(x);
    unsigned short hb = *(unsigned short*)&h;
    unsigned short lsb = (hb >> 8) & 1;
    hb = (unsigned short)(hb + 0x7F + lsb);   // RNE into top 8 bits
    return (uchar)(hb >> 8);
}

__global__ __launch_bounds__(256) void transpose_convert(
    const float* __restrict__ W, uchar* __restrict__ Wt8)
{
    __shared__ float tile[32][33];
    const int f0 = blockIdx.x * 32;
    const int h0 = blockIdx.y * 32;
    const int tx = threadIdx.x;
    const int ty = threadIdx.y;

#pragma unroll
    for (int i = 0; i < 32; i += 8)
        tile[ty + i][tx] = W[(h0 + ty + i) * F_DIM + f0 + tx];
    __syncthreads();
#pragma unroll
    for (int i = 0; i < 32; i += 8)
        Wt8[(size_t)(f0 + ty + i) * H_DIM + h0 + tx] = f32_to_e5m2(tile[tx][ty + i]);
}

// ---------------------------------------------------------------------------
// Main: 1 wave per position (instruction economy of R0) + occupancy of R1.
// Lane c = lane&31 owns h = 16c..16c+15; lanes 0-31 even feature slots,
// 32-63 odd. 8 groups x 4 uint4 gathers, double-buffered (8 loads in
// flight/wave; at 6 waves/SIMD => 48 outstanding per SIMD). Metadata is
// parity-sorted in LDS so each group reads 2x ds_read_b128. Epilogue is
// computed on the fly (no fp32 staging arrays) to keep VGPR <= 84 for
// 6 waves/SIMD.
// ---------------------------------------------------------------------------
__global__ __launch_bounds__(256, 6) void nnue_fwd(
    const int*   __restrict__ stm_idx,
    const int*   __restrict__ nstm_idx,
    const float* __restrict__ stm_val,
    const float* __restrict__ nstm_val,
    const uchar* __restrict__ Wt8,        // [F][H] e5m2
    const float* __restrict__ b_ft,
    const float* __restrict__ W_out,
    const float* __restrict__ b_out,
    float* __restrict__ out)
{
    const int tid  = threadIdx.x;
    const int w    = tid >> 6;
    const int lane = tid & 63;
    const int half = lane >> 5;
    const int c    = lane & 31;
    const int b    = blockIdx.x * 4 + w;
    const int NNZ  = B_SZ * NNZ_PER;

    // sh layout: [w][parity*32 + side*16 + j]  (side 0=stm 1=nstm, j=pair 0..15)
    // entry = {half2(v,v) : f}
    __shared__ uint64 sh[4][64];
    {
        const int base = b * NNZ_PER;
        const int k    = lane & 31;
        int f; float v;
        if (lane < 32) { f = stm_idx [NNZ + base + k]; v = stm_val [base + k]; }
        else           { f = nstm_idx[NNZ + base + k]; v = nstm_val[base + k]; }
        const int side = lane >> 5;
        const int idx  = (k & 1) * 32 + side * 16 + (k >> 1);
        __half2 vv = __float2half2_rn(v);
        sh[w][idx] = ((uint64)(*(uint32*)&vv) << 32) | (uint32)f;
    }
    __syncthreads();

    const uint32 selA = 0x01040004u;   // [0,b0,0,b1] -> half2(h0,h1)
    const uint32 selB = 0x03040204u;   // [0,b2,0,b3] -> half2(h2,h3)
    const uint32 coff = (uint32)c << 4;
    const char*  Wb   = (const char*)Wt8;
    const uint64* meta = &sh[w][half * 32];

    __half2 z = __float2half2_rn(0.f);
    __half2 sa[8] = {z,z,z,z,z,z,z,z};
    __half2 na[8] = {z,z,z,z,z,z,z,z};

    uint4   bufA[4], bufB[4];
    __half2 valA[4], valB[4];

    // Group g (0..3 stm -> sa, 4..7 nstm -> na); pairs j = 4*(g&3)+i.
#define LOAD_GROUP(g, BUF, VAL)                                               \
    {                                                                         \
        const int o = ((g) >= 4 ? 16 : 0) + 4 * ((g) & 3);                    \
        ulonglong2 m0 = *(const ulonglong2*)(meta + o);                       \
        ulonglong2 m1 = *(const ulonglong2*)(meta + o + 2);                   \
        uint64 ee0 = m0.x, ee1 = m0.y, ee2 = m1.x, ee3 = m1.y;                \
        uint64 ee[4] = {ee0, ee1, ee2, ee3};                                  \
        _Pragma("unroll")                                                     \
        for (int i = 0; i < 4; ++i) {                                         \
            uint32 f  = (uint32)ee[i];                                        \
            uint32 v2 = (uint32)(ee[i] >> 32);                                \
            VAL[i] = *(__half2*)&v2;                                          \
            BUF[i] = *(const uint4*)(Wb + (((size_t)f) << 9) + coff);         \
        }                                                                     \
    }

#define FMA_GROUP(BUF, VAL, ACC)                                              \
    {                                                                         \
        _Pragma("unroll")                                                     \
        for (int i = 0; i < 4; ++i) {                                         \
            uint4 wv = BUF[i];                                                \
            __half2 vv = VAL[i];                                              \
            uint32 p;                                                         \
            p = __builtin_amdgcn_perm(0u, wv.x, selA); ACC[0] = __hfma2(*(__half2*)&p, vv, ACC[0]); \
            p = __builtin_amdgcn_perm(0u, wv.x, selB); ACC[1] = __hfma2(*(__half2*)&p, vv, ACC[1]); \
            p = __builtin_amdgcn_perm(0u, wv.y, selA); ACC[2] = __hfma2(*(__half2*)&p, vv, ACC[2]); \
            p = __builtin_amdgcn_perm(0u, wv.y, selB); ACC[3] = __hfma2(*(__half2*)&p, vv, ACC[3]); \
            p = __builtin_amdgcn_perm(0u, wv.z, selA); ACC[4] = __hfma2(*(__half2*)&p, vv, ACC[4]); \
            p = __builtin_amdgcn_perm(0u, wv.z, selB); ACC[5] = __hfma2(*(__half2*)&p, vv, ACC[5]); \
            p = __builtin_amdgcn_perm(0u, wv.w, selA); ACC[6] = __hfma2(*(__half2*)&p, vv, ACC[6]); \
            p = __builtin_amdgcn_perm(0u, wv.w, selB); ACC[7] = __hfma2(*(__half2*)&p, vv, ACC[7]); \
        }                                                                     \
    }

    LOAD_GROUP(0, bufA, valA);
    LOAD_GROUP(1, bufB, valB);
    FMA_GROUP(bufA, valA, sa);
    LOAD_GROUP(2, bufA, valA);
    FMA_GROUP(bufB, valB, sa);
    LOAD_GROUP(3, bufB, valB);
    FMA_GROUP(bufA, valA, sa);
    LOAD_GROUP(4, bufA, valA);
    FMA_GROUP(bufB, valB, sa);
    LOAD_GROUP(5, bufB, valB);
    FMA_GROUP(bufA, valA, na);
    LOAD_GROUP(6, bufA, valA);
    FMA_GROUP(bufB, valB, na);
    LOAD_GROUP(7, bufB, valB);
    FMA_GROUP(bufA, valA, na);
    FMA_GROUP(bufB, valB, na);

#undef LOAD_GROUP
#undef FMA_GROUP

    // Epilogue on the fly. Lane^32 holds the other feature parity for the
    // same h-range. half=0 lanes dot the stm side vs W_out[0:512), half=1
    // the nstm side vs W_out[512:1024); full-wave reduce sums everything.
    const float4* b4 = (const float4*)(b_ft + c * 16);
    const float4* w4 = (const float4*)(W_out + half * H_DIM + c * 16);
    float4 bv[4] = {b4[0], b4[1], b4[2], b4[3]};
    float4 wv4[4] = {w4[0], w4[1], w4[2], w4[3]};
    const float* bias = (const float*)bv;
    const float* wo   = (const float*)wv4;

    float dot = 0.f;
#pragma unroll
    for (int k = 0; k < 8; ++k) {
        int ms = *(int*)&sa[k];
        int mn = *(int*)&na[k];
        int os = __shfl_xor(ms, 32, 64);
        int on = __shfl_xor(mn, 32, 64);
        int mm = half ? mn : ms;
        int oo = half ? on : os;
        __half2 mh = *(__half2*)&mm;
        __half2 oh = *(__half2*)&oo;
        float h0 = __low2float(mh)  + __low2float(oh);
        float h1 = __high2float(mh) + __high2float(oh);
        float a0 = fminf(fmaxf(h0 + bias[2 * k],     0.f), 1.f);
        float a1 = fminf(fmaxf(h1 + bias[2 * k + 1], 0.f), 1.f);
        dot += a0 * wo[2 * k] + a1 * wo[2 * k + 1];
    }

#pragma unroll
    for (int off = 32; off > 0; off >>= 1)
        dot += __shfl_xor(dot, off, 64);

    if (lane == 0)
        out[b] = 1.f / (1.f + expf(-(dot + b_out[0])));
}

extern "C" void kernel_launch(void* const* d_in, const int* in_sizes, int n_in,
                              void* d_out, int out_size, void* d_ws, size_t ws_size,
                              hipStream_t stream) {
    const int*   stm_idx  = (const int*)  d_in[0];
    const int*   nstm_idx = (const int*)  d_in[1];
    const float* stm_val  = (const float*)d_in[2];
    const float* nstm_val = (const float*)d_in[3];
    const float* W_ft     = (const float*)d_in[5];
    const float* b_ft     = (const float*)d_in[6];
    const float* W_out    = (const float*)d_in[7];
    const float* b_out    = (const float*)d_in[8];
    float*       out      = (float*)d_out;
    uchar*       Wt8      = (uchar*)d_ws;   // 384 KiB

    dim3 tb(32, 8);
    dim3 tg(F_DIM / 32, H_DIM / 32);
    transpose_convert<<<tg, tb, 0, stream>>>(W_ft, Wt8);

    nnue_fwd<<<B_SZ / 4, 256, 0, stream>>>(stm_idx, nstm_idx, stm_val, nstm_val,
                                           Wt8, b_ft, W_out, b_out, out);
}